// Round 3
// baseline (211.563 us; speedup 1.0000x reference)
//
#include <hip/hip_runtime.h>

// Problem: out[b,:] = softmax_s( enc[b,s,:] . w2 ),  w2[k] = sum_h v[h]*W[h,2H+k].
// hidden/bias contributions are constant along s -> cancel under softmax(axis=1).
// HBM floor: read enc once = 64*512*1024*4 B = 134 MB (~21 us at 6.3 TB/s).
// Measured dur_us contains ~124 us of harness reset (536 MB ws poison fill at
// ~82 us + 147 MB input restore) -- visible as fillBufferAligned in rocprof.
//
// R2 theory (resubmitted in R3 -- broker timeout, never measured): enc
// (134 MB) fits in the 256 MB Infinity Cache, and the harness re-writes it
// every iteration (restore). R1 used nontemporal loads on enc, which
// forfeits L3 hits. Switch to plain dwordx4 loads -> if enc is L3-resident,
// kernel B beats the HBM rate. Also: kernel A single-stage final w2
// (grid 32, 128-B k-tiles) so B's hoist is 4 loads, not 16.

#define HID 1024
#define BB  64
#define SS  512
#define W3H 3072

typedef float floatx4 __attribute__((ext_vector_type(4)));

// Kernel A: w2[k] = sum_h v[h] * W[h*3072 + 2048 + k]. Grid 32 x 1024 thr.
// Block kt owns k in [32*kt, 32*kt+32). Thread = (hg = t>>5, kl = t&31);
// each thread sums 32 h-values. A wave covers 2 h-rows x 32 consecutive k
// = two full 128-B lines per load. Exact 4 MB fetch.
__global__ __launch_bounds__(1024) void wfold_kernel(
        const float* __restrict__ W, const float* __restrict__ v,
        float* __restrict__ w2) {
    __shared__ float part[32][33];
    const int kl = threadIdx.x & 31;
    const int hg = threadIdx.x >> 5;            // 0..31
    const int k  = blockIdx.x * 32 + kl;
    const int h0 = hg * 32;
    float acc = 0.0f;
    #pragma unroll
    for (int h = h0; h < h0 + 32; ++h)
        acc += v[h] * W[(size_t)h * W3H + 2 * HID + k];
    part[hg][kl] = acc;
    __syncthreads();
    // tree-reduce over hg: 32 -> 16 -> ... -> 1
    for (int half = 16; half >= 1; half >>= 1) {
        if (hg < half) part[hg][kl] += part[hg + half][kl];
        __syncthreads();
    }
    if (threadIdx.x < 32) w2[k] = part[0][kl];
}

// Kernel B: scores[r] = dot(enc[r,:], w2). 2048 blocks x 256 threads.
// Each wave: hoist w2 into 16 VGPRs (4 loads), then 4 contiguous rows with
// plain 16B loads (L3-resident enc should hit Infinity Cache).
__global__ __launch_bounds__(256) void scores_kernel(
        const floatx4* __restrict__ enc4, const floatx4* __restrict__ w24,
        float* __restrict__ scores) {
    const int wave = threadIdx.x >> 6;
    const int lane = threadIdx.x & 63;
    const int wid  = blockIdx.x * 4 + wave;         // wave id in [0, 8192)

    floatx4 w[4];
    #pragma unroll
    for (int i = 0; i < 4; ++i)
        w[i] = w24[i * 64 + lane];

    const floatx4* base = enc4 + (size_t)wid * 4 * (HID / 4);
    float acc[4];
    #pragma unroll
    for (int j = 0; j < 4; ++j) {
        acc[j] = 0.0f;
        #pragma unroll
        for (int i = 0; i < 4; ++i) {
            floatx4 e = base[j * 256 + i * 64 + lane];
            acc[j] += e.x * w[i].x + e.y * w[i].y + e.z * w[i].z + e.w * w[i].w;
        }
    }
    #pragma unroll
    for (int j = 0; j < 4; ++j) {
        float a = acc[j];
        #pragma unroll
        for (int off = 32; off > 0; off >>= 1)
            a += __shfl_down(a, off);
        if (lane == 0) scores[wid * 4 + j] = a;
    }
}

// Kernel C: per-b softmax over 512 scores. One block of 512 threads per b.
__global__ __launch_bounds__(512) void softmax_kernel(
        const float* __restrict__ scores, float* __restrict__ out) {
    __shared__ float red[8];
    const int b = blockIdx.x;
    const int t = threadIdx.x;
    const int wave = t >> 6, lane = t & 63;

    float x = scores[b * SS + t];

    float m = x;
    #pragma unroll
    for (int off = 32; off > 0; off >>= 1)
        m = fmaxf(m, __shfl_down(m, off));
    if (lane == 0) red[wave] = m;
    __syncthreads();
    if (t == 0) {
        float mm = red[0];
        #pragma unroll
        for (int i = 1; i < 8; ++i) mm = fmaxf(mm, red[i]);
        red[0] = mm;
    }
    __syncthreads();
    m = red[0];
    __syncthreads();

    float e = expf(x - m);

    float s = e;
    #pragma unroll
    for (int off = 32; off > 0; off >>= 1)
        s += __shfl_down(s, off);
    if (lane == 0) red[wave] = s;
    __syncthreads();
    if (t == 0) {
        float tot = 0.0f;
        #pragma unroll
        for (int i = 0; i < 8; ++i) tot += red[i];
        red[0] = tot;
    }
    __syncthreads();
    out[b * SS + t] = e / red[0];
}

extern "C" void kernel_launch(void* const* d_in, const int* in_sizes, int n_in,
                              void* d_out, int out_size, void* d_ws, size_t ws_size,
                              hipStream_t stream) {
    // inputs: hidden [2,64,1024] (unused), encoder_outputs [64,512,1024],
    //         W [1024,3072], b [1024] (unused), v [1024]
    const float* enc = (const float*)d_in[1];
    const float* W   = (const float*)d_in[2];
    const float* v   = (const float*)d_in[4];
    float* out = (float*)d_out;

    float* w2     = (float*)d_ws;         // 1024 floats
    float* scores = w2 + HID;             // 32768 floats

    wfold_kernel<<<32, 1024, 0, stream>>>(W, v, w2);

    scores_kernel<<<(BB * SS) / 16, 256, 0, stream>>>(
        (const floatx4*)enc, (const floatx4*)w2, scores);

    softmax_kernel<<<BB, 512, 0, stream>>>(scores, out);
}

// Round 6
// 200.785 us; speedup vs baseline: 1.0537x; 1.0537x over previous
//
#include <hip/hip_runtime.h>

// Problem: out[b,:] = softmax_s( enc[b,s,:] . w2 ),  w2[k] = sum_h v[h]*W[h,2H+k].
// hidden/bias contributions are constant along s -> cancel under softmax(axis=1).
// HBM floor: read enc once = 64*512*1024*4 B = 134 MB (~21 us at 6.3 TB/s).
// dur_us contains ~125 us of harness reset (536 MB poison fill ~77-82 us +
// 147 MB input restore) -- visible as fillBufferAligned in rocprof.
//
// R3 RESULT (measured): plain cached loads on enc REGRESSED ~15-18 us vs
// nontemporal (211.6 vs 198.0, on a faster machine). The 536 MB poison fill
// sweeps L3 before our launch -> enc never L3-resident; cached loads also
// thrash against the fill's dirty lines (forced writebacks). LEARNED FACT:
// stream enc with __builtin_nontemporal_load. This is R4's revert (nt loads
// + single-stage kernel A), resubmitted in R6 after two broker timeouts.

#define HID 1024
#define BB  64
#define SS  512
#define W3H 3072

typedef float floatx4 __attribute__((ext_vector_type(4)));

// Kernel A: w2[k] = sum_h v[h] * W[h*3072 + 2048 + k]. Grid 32 x 1024 thr.
// Block kt owns k in [32*kt, 32*kt+32). Thread = (hg = t>>5, kl = t&31);
// each thread sums 32 h-values. A wave covers 2 h-rows x 32 consecutive k
// = two full 128-B lines per load. Exact 4 MB fetch.
__global__ __launch_bounds__(1024) void wfold_kernel(
        const float* __restrict__ W, const float* __restrict__ v,
        float* __restrict__ w2) {
    __shared__ float part[32][33];
    const int kl = threadIdx.x & 31;
    const int hg = threadIdx.x >> 5;            // 0..31
    const int k  = blockIdx.x * 32 + kl;
    const int h0 = hg * 32;
    float acc = 0.0f;
    #pragma unroll
    for (int h = h0; h < h0 + 32; ++h)
        acc += v[h] * W[(size_t)h * W3H + 2 * HID + k];
    part[hg][kl] = acc;
    __syncthreads();
    // tree-reduce over hg: 32 -> 16 -> ... -> 1
    for (int half = 16; half >= 1; half >>= 1) {
        if (hg < half) part[hg][kl] += part[hg + half][kl];
        __syncthreads();
    }
    if (threadIdx.x < 32) w2[k] = part[0][kl];
}

// Kernel B: scores[r] = dot(enc[r,:], w2). 2048 blocks x 256 threads.
// Each wave: hoist w2 into 16 VGPRs (4 plain loads -- tiny, cached), then
// 4 contiguous rows with 16B NONTEMPORAL loads (enc streamed once; L3 is
// cold+dirty after the poison fill -- do not allocate).
__global__ __launch_bounds__(256) void scores_kernel(
        const floatx4* __restrict__ enc4, const floatx4* __restrict__ w24,
        float* __restrict__ scores) {
    const int wave = threadIdx.x >> 6;
    const int lane = threadIdx.x & 63;
    const int wid  = blockIdx.x * 4 + wave;         // wave id in [0, 8192)

    floatx4 w[4];
    #pragma unroll
    for (int i = 0; i < 4; ++i)
        w[i] = w24[i * 64 + lane];

    const floatx4* base = enc4 + (size_t)wid * 4 * (HID / 4);
    float acc[4];
    #pragma unroll
    for (int j = 0; j < 4; ++j) {
        acc[j] = 0.0f;
        #pragma unroll
        for (int i = 0; i < 4; ++i) {
            floatx4 e = __builtin_nontemporal_load(&base[j * 256 + i * 64 + lane]);
            acc[j] += e.x * w[i].x + e.y * w[i].y + e.z * w[i].z + e.w * w[i].w;
        }
    }
    #pragma unroll
    for (int j = 0; j < 4; ++j) {
        float a = acc[j];
        #pragma unroll
        for (int off = 32; off > 0; off >>= 1)
            a += __shfl_down(a, off);
        if (lane == 0) scores[wid * 4 + j] = a;
    }
}

// Kernel C: per-b softmax over 512 scores. One block of 512 threads per b.
__global__ __launch_bounds__(512) void softmax_kernel(
        const float* __restrict__ scores, float* __restrict__ out) {
    __shared__ float red[8];
    const int b = blockIdx.x;
    const int t = threadIdx.x;
    const int wave = t >> 6, lane = t & 63;

    float x = scores[b * SS + t];

    float m = x;
    #pragma unroll
    for (int off = 32; off > 0; off >>= 1)
        m = fmaxf(m, __shfl_down(m, off));
    if (lane == 0) red[wave] = m;
    __syncthreads();
    if (t == 0) {
        float mm = red[0];
        #pragma unroll
        for (int i = 1; i < 8; ++i) mm = fmaxf(mm, red[i]);
        red[0] = mm;
    }
    __syncthreads();
    m = red[0];
    __syncthreads();

    float e = expf(x - m);

    float s = e;
    #pragma unroll
    for (int off = 32; off > 0; off >>= 1)
        s += __shfl_down(s, off);
    if (lane == 0) red[wave] = s;
    __syncthreads();
    if (t == 0) {
        float tot = 0.0f;
        #pragma unroll
        for (int i = 0; i < 8; ++i) tot += red[i];
        red[0] = tot;
    }
    __syncthreads();
    out[b * SS + t] = e / red[0];
}

extern "C" void kernel_launch(void* const* d_in, const int* in_sizes, int n_in,
                              void* d_out, int out_size, void* d_ws, size_t ws_size,
                              hipStream_t stream) {
    // inputs: hidden [2,64,1024] (unused), encoder_outputs [64,512,1024],
    //         W [1024,3072], b [1024] (unused), v [1024]
    const float* enc = (const float*)d_in[1];
    const float* W   = (const float*)d_in[2];
    const float* v   = (const float*)d_in[4];
    float* out = (float*)d_out;

    float* w2     = (float*)d_ws;         // 1024 floats
    float* scores = w2 + HID;             // 32768 floats

    wfold_kernel<<<32, 1024, 0, stream>>>(W, v, w2);

    scores_kernel<<<(BB * SS) / 16, 256, 0, stream>>>(
        (const floatx4*)enc, (const floatx4*)w2, scores);

    softmax_kernel<<<BB, 512, 0, stream>>>(scores, out);
}